// Round 17
// baseline (125.801 us; speedup 1.0000x reference)
//
#include <hip/hip_runtime.h>
#include <cfloat>
#include <math.h>

#define D_IN 128
#define D_OUT 64
#define NEG_SLOPE 0.2f
#define ROWH 128  // ushorts per hkv row: 64 fp16 (hk) + 64 bf16 (hv) = 256 B
#define SQRT_LOG2E 1.2011224087864498f

typedef _Float16 half2v __attribute__((ext_vector_type(2)));
typedef _Float16 half8 __attribute__((ext_vector_type(8)));
typedef float f32x4 __attribute__((ext_vector_type(4)));

// pack/unpack helpers ---------------------------------------------------------
__device__ __forceinline__ unsigned short f2bf(float x) {
  union { float f; unsigned u; } a; a.f = x;
  unsigned r = a.u + 0x7FFFu + ((a.u >> 16) & 1u);
  return (unsigned short)(r >> 16);
}
__device__ __forceinline__ unsigned short f2h(float x) {
  union { _Float16 h; unsigned short u; } c;
  c.h = (_Float16)x;  // RNE
  return c.u;
}
__device__ __forceinline__ float4 unpack_bf4(uint2 q) {
  union { unsigned u; float f; } t;
  float4 r;
  t.u = q.x << 16;          r.x = t.f;
  t.u = q.x & 0xFFFF0000u;  r.y = t.f;
  t.u = q.y << 16;          r.z = t.f;
  t.u = q.y & 0xFFFF0000u;  r.w = t.f;
  return r;
}
// fp16-pair dot with f32 accumulate via v_dot2_f32_f16
__device__ __forceinline__ float hdot4(uint2 a, uint2 b) {
  union { unsigned u; half2v h; } al, ah, bl, bh;
  al.u = a.x; ah.u = a.y; bl.u = b.x; bh.u = b.y;
#if __has_builtin(__builtin_amdgcn_fdot2)
  return __builtin_amdgcn_fdot2(al.h, bl.h,
         __builtin_amdgcn_fdot2(ah.h, bh.h, 0.f, false), false);
#else
  return (float)al.h[0] * (float)bl.h[0] + (float)al.h[1] * (float)bl.h[1] +
         (float)ah.h[0] * (float)bh.h[0] + (float)ah.h[1] * (float)bh.h[1];
#endif
}

// ---------------------------------------------------------------------------
// Kernel P: pack W (f32) into per-lane MFMA B-fragments (fp16).
// Wk pre-scaled by sqrt(log2 e) so gathered score dots land in exp2 domain.
// ---------------------------------------------------------------------------
__global__ void bfrag_kernel(const float* __restrict__ Wk,
                             const float* __restrict__ Wv,
                             _Float16* __restrict__ bfrag) {
  const int idx = blockIdx.x * 256 + threadIdx.x;
  if (idx >= 2048) return;
  const int which = idx >> 10;
  const float* __restrict__ W = which ? Wv : Wk;
  const float scale = which ? 1.0f : SQRT_LOG2E;
  const int li = idx & 1023;
  const int lane = li & 63;
  const int nt = (li >> 6) & 3;
  const int k0i = li >> 8;
  const int col = nt * 16 + (lane & 15);
  const int kbase = k0i * 32 + (lane >> 4) * 8;
  half8 h;
#pragma unroll
  for (int j = 0; j < 8; ++j)
    h[j] = (_Float16)(W[(size_t)(kbase + j) * D_OUT + col] * scale);
  reinterpret_cast<half8*>(bfrag)[idx] = h;
}

// ---------------------------------------------------------------------------
// Kernel A: H = X @ W + b via mfma_f32_16x16x32_f16 (R11/R16 verbatim).
// which==0 -> fp16 hk (pre-scaled by sqrt(log2e)); which==1 -> bf16 hv.
// ---------------------------------------------------------------------------
__global__ __launch_bounds__(256) void linear_mfma_kernel(
    const float* __restrict__ Xk, const float* __restrict__ Xv,
    const float* __restrict__ Wk, const float* __restrict__ bk,
    const float* __restrict__ Wv, const float* __restrict__ bv,
    const _Float16* __restrict__ bfrag, unsigned short* __restrict__ hkv,
    int R, int nblk) {
  const int which = (blockIdx.x >= nblk) ? 1 : 0;
  const int blk = blockIdx.x - which * nblk;
  const float* __restrict__ X = which ? Xv : Xk;
  const float* __restrict__ bias = which ? bv : bk;
  const float bscale = which ? 1.0f : SQRT_LOG2E;
  const int uoff = which ? D_OUT : 0;

  const int wave = threadIdx.x >> 6;
  const int lane = threadIdx.x & 63;
  const int r0 = (blk * 4 + wave) * 16;
  if (r0 >= R) return;
  const int rowi = lane & 15;
  const int kgrp = lane >> 4;

  if (r0 + 16 <= R) {
    const half8* btab =
        reinterpret_cast<const half8*>(bfrag) + (which ? 1024 : 0);
    half8 bf[4][4];
#pragma unroll
    for (int k0i = 0; k0i < 4; ++k0i)
#pragma unroll
      for (int nt = 0; nt < 4; ++nt)
        bf[k0i][nt] = btab[(k0i * 4 + nt) * 64 + lane];

    f32x4 acc[4];
#pragma unroll
    for (int nt = 0; nt < 4; ++nt) acc[nt] = (f32x4){0.f, 0.f, 0.f, 0.f};

    const float* xrow = X + (size_t)(r0 + rowi) * D_IN;
#pragma unroll
    for (int k0i = 0; k0i < 4; ++k0i) {
      const float4 x0 =
          *reinterpret_cast<const float4*>(xrow + k0i * 32 + kgrp * 8);
      const float4 x1 =
          *reinterpret_cast<const float4*>(xrow + k0i * 32 + kgrp * 8 + 4);
      half8 a;
      a[0] = (_Float16)x0.x; a[1] = (_Float16)x0.y;
      a[2] = (_Float16)x0.z; a[3] = (_Float16)x0.w;
      a[4] = (_Float16)x1.x; a[5] = (_Float16)x1.y;
      a[6] = (_Float16)x1.z; a[7] = (_Float16)x1.w;
#pragma unroll
      for (int nt = 0; nt < 4; ++nt)
        acc[nt] = __builtin_amdgcn_mfma_f32_16x16x32_f16(a, bf[k0i][nt],
                                                         acc[nt], 0, 0, 0);
    }
#pragma unroll
    for (int nt = 0; nt < 4; ++nt) {
      const int col = nt * 16 + rowi;
      const float bcol = bias[col] * bscale;
#pragma unroll
      for (int r = 0; r < 4; ++r) {
        const int row = r0 + kgrp * 4 + r;
        const float val = acc[nt][r] + bcol;
        hkv[(size_t)row * ROWH + uoff + col] =
            which ? f2bf(val) : f2h(val);
      }
    }
  } else {
    const float* __restrict__ W = which ? Wv : Wk;
    for (int r = r0; r < R; ++r) {
      const float* xr = X + (size_t)r * D_IN;
      float acc = bias[lane];
      for (int k = 0; k < D_IN; ++k)
        acc = fmaf(xr[k], W[(size_t)k * D_OUT + lane], acc);
      acc *= bscale;
      hkv[(size_t)r * ROWH + uoff + lane] = which ? f2bf(acc) : f2h(acc);
    }
  }
}

// ---------------------------------------------------------------------------
// Kernel B: CSR row pointers from sorted dst.
// ---------------------------------------------------------------------------
__global__ void rowptr_kernel(const int* __restrict__ dst, int E, int N,
                              int* __restrict__ row_ptr) {
  int i = blockIdx.x * blockDim.x + threadIdx.x;
  if (i > N) return;
  int lo = 0, hi = E;
  while (lo < hi) {
    int mid = (lo + hi) >> 1;
    if (dst[mid] < i) lo = mid + 1; else hi = mid;
  }
  row_ptr[i] = lo;
}

// ---------------------------------------------------------------------------
// sum over each 16-lane row via DPP rotate-adds (pure VALU).
// ---------------------------------------------------------------------------
__device__ __forceinline__ float rowsum16(float p) {
  union { float f; int i; } u, v;
  u.f = p;
  v.i = __builtin_amdgcn_update_dpp(0, u.i, 0x121, 0xF, 0xF, true);  // row_ror:1
  u.f += v.f;
  v.i = __builtin_amdgcn_update_dpp(0, u.i, 0x122, 0xF, 0xF, true);  // row_ror:2
  u.f += v.f;
  v.i = __builtin_amdgcn_update_dpp(0, u.i, 0x124, 0xF, 0xF, true);  // row_ror:4
  u.f += v.f;
  v.i = __builtin_amdgcn_update_dpp(0, u.i, 0x128, 0xF, 0xF, true);  // row_ror:8
  u.f += v.f;
  return u.f;
}

// ---------------------------------------------------------------------------
// Pass S: edge-parallel scores. Group of 16 lanes handles 2 consecutive
// edges x both batches (8 independent k-gathers in flight per wave-iter).
// No softmax state, no branches, no merges -> pure TLP latency hiding.
// Touches only the k half-lines (25.6 MB working set).
// ---------------------------------------------------------------------------
__global__ __launch_bounds__(256) void score_kernel(
    const unsigned short* __restrict__ hkv, const int* __restrict__ src,
    const int* __restrict__ dst, float* __restrict__ p0,
    float* __restrict__ p1, int N, int E) {
  const int lane = threadIdx.x & 63;
  const int li = lane & 15;
  const int g = lane >> 4;
  const int wid = blockIdx.x * 4 + (threadIdx.x >> 6);
  const int stride = gridDim.x * 32;  // 4 waves x 8 edges per block
  const unsigned short* hb0 = hkv;
  const unsigned short* hb1 = hkv + (size_t)N * ROWH;

  for (int e = wid * 8 + g * 2; e < E; e += stride) {
    const bool two = (e + 1 < E);
    const int eB = two ? e + 1 : e;
    const int sA = src[e], dA = dst[e];
    const int sB = src[eB], dB = dst[eB];
    const uint2 ksA0 = reinterpret_cast<const uint2*>(hb0 + (size_t)sA * ROWH)[li];
    const uint2 kdA0 = reinterpret_cast<const uint2*>(hb0 + (size_t)dA * ROWH)[li];
    const uint2 ksA1 = reinterpret_cast<const uint2*>(hb1 + (size_t)sA * ROWH)[li];
    const uint2 kdA1 = reinterpret_cast<const uint2*>(hb1 + (size_t)dA * ROWH)[li];
    const uint2 ksB0 = reinterpret_cast<const uint2*>(hb0 + (size_t)sB * ROWH)[li];
    const uint2 kdB0 = reinterpret_cast<const uint2*>(hb0 + (size_t)dB * ROWH)[li];
    const uint2 ksB1 = reinterpret_cast<const uint2*>(hb1 + (size_t)sB * ROWH)[li];
    const uint2 kdB1 = reinterpret_cast<const uint2*>(hb1 + (size_t)dB * ROWH)[li];
    const float pA0 = rowsum16(hdot4(ksA0, kdA0));
    const float pA1 = rowsum16(hdot4(ksA1, kdA1));
    const float pB0 = rowsum16(hdot4(ksB0, kdB0));
    const float pB1 = rowsum16(hdot4(ksB1, kdB1));
    if (li == 0) {
      p0[e] = pA0;
      p1[e] = pA1;
      if (two) { p0[eB] = pB0; p1[eB] = pB1; }
    }
  }
}

// ---------------------------------------------------------------------------
// Pass N: per-(node,batch) softmax normalization over contiguous p range.
// p[e] <- exp2(p[e] - m) / l.  Reads are L2-hot (6.4 MB linear).
// ---------------------------------------------------------------------------
__global__ void norm_kernel(const int* __restrict__ row_ptr,
                            float* __restrict__ p0, float* __restrict__ p1,
                            int N) {
  const int t = blockIdx.x * 256 + threadIdx.x;
  if (t >= 2 * N) return;
  const int node = (t >= N) ? t - N : t;
  float* __restrict__ p = (t >= N) ? p1 : p0;
  const int e0 = row_ptr[node];
  const int e1 = row_ptr[node + 1];
  if (e0 >= e1) return;
  float m = -FLT_MAX;
  for (int e = e0; e < e1; ++e) m = fmaxf(m, p[e]);
  float l = 0.f;
  for (int e = e0; e < e1; ++e) l += exp2f(p[e] - m);
  const float inv = 1.f / l;  // l >= 1 (max term = 1)
  for (int e = e0; e < e1; ++e) p[e] = exp2f(p[e] - m) * inv;
}

// ---------------------------------------------------------------------------
// Pass A: per-node weighted sum of hv rows (no softmax state). Wave = 1 node;
// 4 groups = 2 edge-slots x 2 batches; 2 chains per group -> 8 v-gathers in
// flight. Epilogue: pure adds (slot merge via 1 shfl step). LeakyReLU here.
// Touches only the v half-lines (25.6 MB working set).
// ---------------------------------------------------------------------------
__global__ __launch_bounds__(256) void wsum_kernel(
    const unsigned short* __restrict__ hkv, const int* __restrict__ src,
    const int* __restrict__ row_ptr, const float* __restrict__ p0,
    const float* __restrict__ p1, float* __restrict__ out, int N) {
  const int node = blockIdx.x * 4 + (threadIdx.x >> 6);
  const int lane = threadIdx.x & 63;
  if (node >= N) return;
  const int li = lane & 15;
  const int g = lane >> 4;
  const int slot = g & 1;
  const int batch = g >> 1;
  const unsigned short* hv = hkv + (size_t)batch * N * ROWH + D_OUT;  // v half
  const float* __restrict__ w = batch ? p1 : p0;
  const int e0 = row_ptr[node];
  const int e1 = row_ptr[node + 1];

  float4 aA = {0.f, 0.f, 0.f, 0.f}, aB = {0.f, 0.f, 0.f, 0.f};
  int e = e0 + slot;
  for (; e + 2 < e1; e += 4) {
    const int sA = src[e], sB = src[e + 2];
    const float wA = w[e], wB = w[e + 2];
    const uint2 vA = reinterpret_cast<const uint2*>(hv + (size_t)sA * ROWH)[li];
    const uint2 vB = reinterpret_cast<const uint2*>(hv + (size_t)sB * ROWH)[li];
    const float4 fA = unpack_bf4(vA);
    const float4 fB = unpack_bf4(vB);
    aA.x = fmaf(wA, fA.x, aA.x); aA.y = fmaf(wA, fA.y, aA.y);
    aA.z = fmaf(wA, fA.z, aA.z); aA.w = fmaf(wA, fA.w, aA.w);
    aB.x = fmaf(wB, fB.x, aB.x); aB.y = fmaf(wB, fB.y, aB.y);
    aB.z = fmaf(wB, fB.z, aB.z); aB.w = fmaf(wB, fB.w, aB.w);
  }
  if (e < e1) {
    const int sA = src[e];
    const float wA = w[e];
    const uint2 vA = reinterpret_cast<const uint2*>(hv + (size_t)sA * ROWH)[li];
    const float4 fA = unpack_bf4(vA);
    aA.x = fmaf(wA, fA.x, aA.x); aA.y = fmaf(wA, fA.y, aA.y);
    aA.z = fmaf(wA, fA.z, aA.z); aA.w = fmaf(wA, fA.w, aA.w);
  }

  aA.x += aB.x; aA.y += aB.y; aA.z += aB.z; aA.w += aB.w;
  // merge edge-slots (lane ^ 16 flips the slot bit)
  aA.x += __shfl_xor(aA.x, 16, 64);
  aA.y += __shfl_xor(aA.y, 16, 64);
  aA.z += __shfl_xor(aA.z, 16, 64);
  aA.w += __shfl_xor(aA.w, 16, 64);

  if (slot == 0) {
    float4 o = aA;
    o.x = (o.x >= 0.f) ? o.x : NEG_SLOPE * o.x;
    o.y = (o.y >= 0.f) ? o.y : NEG_SLOPE * o.y;
    o.z = (o.z >= 0.f) ? o.z : NEG_SLOPE * o.z;
    o.w = (o.w >= 0.f) ? o.w : NEG_SLOPE * o.w;
    *reinterpret_cast<float4*>(out + ((size_t)batch * N + node) * D_OUT +
                               4 * li) = o;
  }
}

// ---------------------------------------------------------------------------
extern "C" void kernel_launch(void* const* d_in, const int* in_sizes, int n_in,
                              void* d_out, int out_size, void* d_ws,
                              size_t ws_size, hipStream_t stream) {
  const float* X_key   = (const float*)d_in[0];
  const float* X_value = (const float*)d_in[1];
  const float* Wk      = (const float*)d_in[2];
  const float* bk      = (const float*)d_in[3];
  const float* Wv      = (const float*)d_in[4];
  const float* bv      = (const float*)d_in[5];
  const int*   src     = (const int*)d_in[6];
  const int*   dst     = (const int*)d_in[7];
  float* out = (float*)d_out;

  const int B = 2;
  const int R = in_sizes[0] / D_IN;  // B*N rows
  const int N = R / B;
  const int E = in_sizes[6];

  // workspace: bfrag 32KB | hkv ushort[R][128] | row_ptr | p0[E] | p1[E]
  _Float16* bfrag = (_Float16*)d_ws;
  unsigned short* hkv = (unsigned short*)((char*)d_ws + 32768);
  int* row_ptr = (int*)(hkv + (size_t)R * ROWH);
  float* p0 = (float*)(row_ptr + (N + 2));
  float* p1 = p0 + E;

  const int blocksB = (N + 1 + 255) / 256;
  hipLaunchKernelGGL(rowptr_kernel, dim3(blocksB), dim3(256), 0, stream,
                     dst, E, N, row_ptr);
  hipLaunchKernelGGL(bfrag_kernel, dim3(8), dim3(256), 0, stream,
                     Wk, Wv, bfrag);
  const int wavesPerMat = (R + 15) / 16;
  const int nblk = (wavesPerMat + 3) / 4;
  hipLaunchKernelGGL(linear_mfma_kernel, dim3(2 * nblk), dim3(256), 0, stream,
                     X_key, X_value, Wk, bk, Wv, bv, bfrag, hkv, R, nblk);
  hipLaunchKernelGGL(score_kernel, dim3(2048), dim3(256), 0, stream,
                     hkv, src, dst, p0, p1, N, E);
  const int blocksN = (2 * N + 255) / 256;
  hipLaunchKernelGGL(norm_kernel, dim3(blocksN), dim3(256), 0, stream,
                     row_ptr, p0, p1, N);
  const int blocksW = (N + 3) / 4;
  hipLaunchKernelGGL(wsum_kernel, dim3(blocksW), dim3(256), 0, stream,
                     hkv, src, row_ptr, p0, p1, out, N);
}

// Round 18
// 122.196 us; speedup vs baseline: 1.0295x; 1.0295x over previous
//
#include <hip/hip_runtime.h>
#include <cfloat>
#include <math.h>

#define D_IN 128
#define D_OUT 64
#define NEG_SLOPE 0.2f
#define ROWH 128  // ushorts per hkv row: 64 fp16 (hk) + 64 bf16 (hv) = 256 B
#define SQRT_LOG2E 1.2011224087864498f

typedef _Float16 half2v __attribute__((ext_vector_type(2)));
typedef _Float16 half8 __attribute__((ext_vector_type(8)));
typedef float f32x4 __attribute__((ext_vector_type(4)));

// pack/unpack helpers ---------------------------------------------------------
__device__ __forceinline__ unsigned short f2bf(float x) {
  union { float f; unsigned u; } a; a.f = x;
  unsigned r = a.u + 0x7FFFu + ((a.u >> 16) & 1u);
  return (unsigned short)(r >> 16);
}
__device__ __forceinline__ unsigned short f2h(float x) {
  union { _Float16 h; unsigned short u; } c;
  c.h = (_Float16)x;  // RNE
  return c.u;
}
__device__ __forceinline__ float4 unpack_bf4(uint2 q) {
  union { unsigned u; float f; } t;
  float4 r;
  t.u = q.x << 16;          r.x = t.f;
  t.u = q.x & 0xFFFF0000u;  r.y = t.f;
  t.u = q.y << 16;          r.z = t.f;
  t.u = q.y & 0xFFFF0000u;  r.w = t.f;
  return r;
}
// fp16-pair dot with f32 accumulate via v_dot2_f32_f16
__device__ __forceinline__ float hdot4(uint2 a, uint2 b) {
  union { unsigned u; half2v h; } al, ah, bl, bh;
  al.u = a.x; ah.u = a.y; bl.u = b.x; bh.u = b.y;
#if __has_builtin(__builtin_amdgcn_fdot2)
  return __builtin_amdgcn_fdot2(al.h, bl.h,
         __builtin_amdgcn_fdot2(ah.h, bh.h, 0.f, false), false);
#else
  return (float)al.h[0] * (float)bl.h[0] + (float)al.h[1] * (float)bl.h[1] +
         (float)ah.h[0] * (float)bh.h[0] + (float)ah.h[1] * (float)bh.h[1];
#endif
}

// ---------------------------------------------------------------------------
// Kernel P: pack W (f32) into per-lane MFMA B-fragments (fp16).
// Wk pre-scaled by sqrt(log2 e) so gathered score dots land in exp2 domain.
// ---------------------------------------------------------------------------
__global__ void bfrag_kernel(const float* __restrict__ Wk,
                             const float* __restrict__ Wv,
                             _Float16* __restrict__ bfrag) {
  const int idx = blockIdx.x * 256 + threadIdx.x;
  if (idx >= 2048) return;
  const int which = idx >> 10;
  const float* __restrict__ W = which ? Wv : Wk;
  const float scale = which ? 1.0f : SQRT_LOG2E;
  const int li = idx & 1023;
  const int lane = li & 63;
  const int nt = (li >> 6) & 3;
  const int k0i = li >> 8;
  const int col = nt * 16 + (lane & 15);
  const int kbase = k0i * 32 + (lane >> 4) * 8;
  half8 h;
#pragma unroll
  for (int j = 0; j < 8; ++j)
    h[j] = (_Float16)(W[(size_t)(kbase + j) * D_OUT + col] * scale);
  reinterpret_cast<half8*>(bfrag)[idx] = h;
}

// ---------------------------------------------------------------------------
// Kernel A: H = X @ W + b via mfma_f32_16x16x32_f16 (R11/R16 verbatim).
// which==0 -> fp16 hk (pre-scaled by sqrt(log2e)); which==1 -> bf16 hv.
// ---------------------------------------------------------------------------
__global__ __launch_bounds__(256) void linear_mfma_kernel(
    const float* __restrict__ Xk, const float* __restrict__ Xv,
    const float* __restrict__ Wk, const float* __restrict__ bk,
    const float* __restrict__ Wv, const float* __restrict__ bv,
    const _Float16* __restrict__ bfrag, unsigned short* __restrict__ hkv,
    int R, int nblk) {
  const int which = (blockIdx.x >= nblk) ? 1 : 0;
  const int blk = blockIdx.x - which * nblk;
  const float* __restrict__ X = which ? Xv : Xk;
  const float* __restrict__ bias = which ? bv : bk;
  const float bscale = which ? 1.0f : SQRT_LOG2E;
  const int uoff = which ? D_OUT : 0;

  const int wave = threadIdx.x >> 6;
  const int lane = threadIdx.x & 63;
  const int r0 = (blk * 4 + wave) * 16;
  if (r0 >= R) return;
  const int rowi = lane & 15;
  const int kgrp = lane >> 4;

  if (r0 + 16 <= R) {
    const half8* btab =
        reinterpret_cast<const half8*>(bfrag) + (which ? 1024 : 0);
    half8 bf[4][4];
#pragma unroll
    for (int k0i = 0; k0i < 4; ++k0i)
#pragma unroll
      for (int nt = 0; nt < 4; ++nt)
        bf[k0i][nt] = btab[(k0i * 4 + nt) * 64 + lane];

    f32x4 acc[4];
#pragma unroll
    for (int nt = 0; nt < 4; ++nt) acc[nt] = (f32x4){0.f, 0.f, 0.f, 0.f};

    const float* xrow = X + (size_t)(r0 + rowi) * D_IN;
#pragma unroll
    for (int k0i = 0; k0i < 4; ++k0i) {
      const float4 x0 =
          *reinterpret_cast<const float4*>(xrow + k0i * 32 + kgrp * 8);
      const float4 x1 =
          *reinterpret_cast<const float4*>(xrow + k0i * 32 + kgrp * 8 + 4);
      half8 a;
      a[0] = (_Float16)x0.x; a[1] = (_Float16)x0.y;
      a[2] = (_Float16)x0.z; a[3] = (_Float16)x0.w;
      a[4] = (_Float16)x1.x; a[5] = (_Float16)x1.y;
      a[6] = (_Float16)x1.z; a[7] = (_Float16)x1.w;
#pragma unroll
      for (int nt = 0; nt < 4; ++nt)
        acc[nt] = __builtin_amdgcn_mfma_f32_16x16x32_f16(a, bf[k0i][nt],
                                                         acc[nt], 0, 0, 0);
    }
#pragma unroll
    for (int nt = 0; nt < 4; ++nt) {
      const int col = nt * 16 + rowi;
      const float bcol = bias[col] * bscale;
#pragma unroll
      for (int r = 0; r < 4; ++r) {
        const int row = r0 + kgrp * 4 + r;
        const float val = acc[nt][r] + bcol;
        hkv[(size_t)row * ROWH + uoff + col] =
            which ? f2bf(val) : f2h(val);
      }
    }
  } else {
    const float* __restrict__ W = which ? Wv : Wk;
    for (int r = r0; r < R; ++r) {
      const float* xr = X + (size_t)r * D_IN;
      float acc = bias[lane];
      for (int k = 0; k < D_IN; ++k)
        acc = fmaf(xr[k], W[(size_t)k * D_OUT + lane], acc);
      acc *= bscale;
      hkv[(size_t)r * ROWH + uoff + lane] = which ? f2bf(acc) : f2h(acc);
    }
  }
}

// ---------------------------------------------------------------------------
// Kernel B: CSR row pointers from sorted dst.
// ---------------------------------------------------------------------------
__global__ void rowptr_kernel(const int* __restrict__ dst, int E, int N,
                              int* __restrict__ row_ptr) {
  int i = blockIdx.x * blockDim.x + threadIdx.x;
  if (i > N) return;
  int lo = 0, hi = E;
  while (lo < hi) {
    int mid = (lo + hi) >> 1;
    if (dst[mid] < i) lo = mid + 1; else hi = mid;
  }
  row_ptr[i] = lo;
}

// ---------------------------------------------------------------------------
// sum over each 16-lane row via DPP rotate-adds (pure VALU).
// ---------------------------------------------------------------------------
__device__ __forceinline__ float rowsum16(float p) {
  union { float f; int i; } u, v;
  u.f = p;
  v.i = __builtin_amdgcn_update_dpp(0, u.i, 0x121, 0xF, 0xF, true);  // row_ror:1
  u.f += v.f;
  v.i = __builtin_amdgcn_update_dpp(0, u.i, 0x122, 0xF, 0xF, true);  // row_ror:2
  u.f += v.f;
  v.i = __builtin_amdgcn_update_dpp(0, u.i, 0x124, 0xF, 0xF, true);  // row_ror:4
  u.f += v.f;
  v.i = __builtin_amdgcn_update_dpp(0, u.i, 0x128, 0xF, 0xF, true);  // row_ror:8
  u.f += v.f;
  return u.f;
}

// online-softmax state, exp2 domain (hk pre-scaled so dot is log2-weighted)
struct SMState { float m, l; float4 a; };

__device__ __forceinline__ void sm_update(SMState& st, float pl,
                                          const uint2& vu) {
  if (pl > st.m) {
    const float sc = exp2f(st.m - pl);  // first edge: exp2(-inf) = 0
    st.l *= sc;
    st.a.x *= sc; st.a.y *= sc; st.a.z *= sc; st.a.w *= sc;
    st.m = pl;
  }
  const float a = exp2f(pl - st.m);
  const float4 vs = unpack_bf4(vu);
  st.l += a;
  st.a.x = fmaf(a, vs.x, st.a.x);
  st.a.y = fmaf(a, vs.y, st.a.y);
  st.a.z = fmaf(a, vs.z, st.a.z);
  st.a.w = fmaf(a, vs.w, st.a.w);
}

__device__ __forceinline__ void sm_merge(SMState& d, const SMState& s) {
  const float mn = fmaxf(d.m, s.m);
  const float s1 = exp2f(d.m - mn);
  const float s2 = exp2f(s.m - mn);
  d.l = d.l * s1 + s.l * s2;
  d.a.x = d.a.x * s1 + s.a.x * s2;
  d.a.y = d.a.y * s1 + s.a.y * s2;
  d.a.z = d.a.z * s1 + s.a.z * s2;
  d.a.w = d.a.w * s1 + s.a.w * s2;
  d.m = mn;
}

__device__ __forceinline__ void sm_merge_xor(SMState& d, int off) {
  SMState s;
  s.m = __shfl_xor(d.m, off, 64);
  s.l = __shfl_xor(d.l, off, 64);
  s.a.x = __shfl_xor(d.a.x, off, 64);
  s.a.y = __shfl_xor(d.a.y, off, 64);
  s.a.z = __shfl_xor(d.a.z, off, 64);
  s.a.w = __shfl_xor(d.a.w, off, 64);
  sm_merge(d, s);
}

// one edge-visit: k uint2 + v uint2 (independent loads)
__device__ __forceinline__ void edge_proc(const unsigned short* __restrict__ hb,
                                          int s, int li, const uint2& kd,
                                          SMState& st) {
  const uint2* r = reinterpret_cast<const uint2*>(hb + (size_t)s * ROWH);
  const uint2 kq = r[li];
  const uint2 vq = r[16 + li];
  const float pl = rowsum16(hdot4(kq, kd));
  sm_update(st, pl, vq);
}

// ---------------------------------------------------------------------------
// Kernel C: batch-partitioned XCD-aware aggregation.
// Blocks with (blockIdx%8)<4 handle batch 0, else batch 1 -> each XCD's L2
// only touches ONE batch's 12.8 MB (predicted FETCH 180 -> ~105 MB).
// Wave = one (node,batch); 4 groups of 16 lanes = 4 edge slots; 4 ILP chains
// per slot (stride 4) -> 8 loads in flight per iteration (R16-equal MLP).
// ---------------------------------------------------------------------------
__global__ __launch_bounds__(256) void aggregate_kernel(
    const unsigned short* __restrict__ hkv, const int* __restrict__ src,
    const int* __restrict__ row_ptr, float* __restrict__ out, int N,
    int nb4) {
  const int b8 = blockIdx.x & 7;
  const int batch = b8 >> 2;
  const int idx = (blockIdx.x >> 3) * 4 + (b8 & 3);  // block index in batch
  if (idx >= nb4) return;
  const int node = idx * 4 + (threadIdx.x >> 6);
  const int lane = threadIdx.x & 63;
  if (node >= N) return;

  const unsigned short* hb = hkv + (size_t)batch * N * ROWH;
  const int li = lane & 15;  // dim-quad index (uint2 granule)
  const int g = lane >> 4;   // edge slot

  const uint2 kd = reinterpret_cast<const uint2*>(hb + (size_t)node * ROWH)[li];
  const int e0 = row_ptr[node];
  const int e1 = row_ptr[node + 1];

  SMState A = {-FLT_MAX, 0.f, {0.f, 0.f, 0.f, 0.f}};
  SMState B = A, C = A, D = A;

  int e = e0 + g;
  // main loop: 4 chains x stride 4 -> 16 edges per iteration, 8 loads in
  // flight (4 k + 4 v). For the mean degree (16) this is exactly 1 iter.
  for (; e + 12 < e1; e += 16) {
    const int sA = src[e];
    const int sB = src[e + 4];
    const int sC = src[e + 8];
    const int sD = src[e + 12];
    edge_proc(hb, sA, li, kd, A);
    edge_proc(hb, sB, li, kd, B);
    edge_proc(hb, sC, li, kd, C);
    edge_proc(hb, sD, li, kd, D);
  }
  for (; e < e1; e += 4) edge_proc(hb, src[e], li, kd, A);

  sm_merge(A, B);
  sm_merge(C, D);
  sm_merge(A, C);
  sm_merge_xor(A, 16);
  sm_merge_xor(A, 32);

  if (lane < 16) {
    const float denom = (A.l == 0.f) ? 1.f : A.l;
    float4 o;
    o.x = A.a.x / denom; o.y = A.a.y / denom;
    o.z = A.a.z / denom; o.w = A.a.w / denom;
    o.x = (o.x >= 0.f) ? o.x : NEG_SLOPE * o.x;
    o.y = (o.y >= 0.f) ? o.y : NEG_SLOPE * o.y;
    o.z = (o.z >= 0.f) ? o.z : NEG_SLOPE * o.z;
    o.w = (o.w >= 0.f) ? o.w : NEG_SLOPE * o.w;
    *reinterpret_cast<float4*>(out + ((size_t)batch * N + node) * D_OUT +
                               4 * lane) = o;
  }
}

// ---------------------------------------------------------------------------
extern "C" void kernel_launch(void* const* d_in, const int* in_sizes, int n_in,
                              void* d_out, int out_size, void* d_ws,
                              size_t ws_size, hipStream_t stream) {
  const float* X_key   = (const float*)d_in[0];
  const float* X_value = (const float*)d_in[1];
  const float* Wk      = (const float*)d_in[2];
  const float* bk      = (const float*)d_in[3];
  const float* Wv      = (const float*)d_in[4];
  const float* bv      = (const float*)d_in[5];
  const int*   src     = (const int*)d_in[6];
  const int*   dst     = (const int*)d_in[7];
  float* out = (float*)d_out;

  const int B = 2;
  const int R = in_sizes[0] / D_IN;  // B*N rows
  const int N = R / B;
  const int E = in_sizes[6];

  // workspace: bfrag 32KB (16B-aligned) | hkv ushort[R][128] | row_ptr
  _Float16* bfrag = (_Float16*)d_ws;
  unsigned short* hkv = (unsigned short*)((char*)d_ws + 32768);
  int* row_ptr = (int*)(hkv + (size_t)R * ROWH);

  const int blocksB = (N + 1 + 255) / 256;
  hipLaunchKernelGGL(rowptr_kernel, dim3(blocksB), dim3(256), 0, stream,
                     dst, E, N, row_ptr);
  hipLaunchKernelGGL(bfrag_kernel, dim3(8), dim3(256), 0, stream,
                     Wk, Wv, bfrag);
  const int wavesPerMat = (R + 15) / 16;
  const int nblk = (wavesPerMat + 3) / 4;
  hipLaunchKernelGGL(linear_mfma_kernel, dim3(2 * nblk), dim3(256), 0, stream,
                     X_key, X_value, Wk, bk, Wv, bv, bfrag, hkv, R, nblk);
  const int nb4 = (N + 3) / 4;                 // blocks per batch
  const int blocksC = ((2 * nb4 + 7) / 8) * 8; // pad to XCD-group multiple
  hipLaunchKernelGGL(aggregate_kernel, dim3(blocksC), dim3(256), 0, stream,
                     hkv, src, row_ptr, out, N, nb4);
}

// Round 19
// 100.159 us; speedup vs baseline: 1.2560x; 1.2200x over previous
//
#include <hip/hip_runtime.h>
#include <cfloat>
#include <math.h>

#define D_IN 128
#define D_OUT 64
#define NEG_SLOPE 0.2f
#define ROWH 128  // ushorts per hkv row: 64 fp16 (hk) + 64 bf16 (hv) = 256 B
#define SQRT_LOG2E 1.2011224087864498f

typedef _Float16 half2v __attribute__((ext_vector_type(2)));
typedef _Float16 half8 __attribute__((ext_vector_type(8)));
typedef float f32x4 __attribute__((ext_vector_type(4)));

// pack/unpack helpers ---------------------------------------------------------
__device__ __forceinline__ unsigned short f2bf(float x) {
  union { float f; unsigned u; } a; a.f = x;
  unsigned r = a.u + 0x7FFFu + ((a.u >> 16) & 1u);
  return (unsigned short)(r >> 16);
}
__device__ __forceinline__ unsigned short f2h(float x) {
  union { _Float16 h; unsigned short u; } c;
  c.h = (_Float16)x;  // RNE
  return c.u;
}
__device__ __forceinline__ float4 unpack_bf4(uint2 q) {
  union { unsigned u; float f; } t;
  float4 r;
  t.u = q.x << 16;          r.x = t.f;
  t.u = q.x & 0xFFFF0000u;  r.y = t.f;
  t.u = q.y << 16;          r.z = t.f;
  t.u = q.y & 0xFFFF0000u;  r.w = t.f;
  return r;
}
// fp16-pair dot with f32 accumulate via v_dot2_f32_f16
__device__ __forceinline__ float hdot4(uint2 a, uint2 b) {
  union { unsigned u; half2v h; } al, ah, bl, bh;
  al.u = a.x; ah.u = a.y; bl.u = b.x; bh.u = b.y;
#if __has_builtin(__builtin_amdgcn_fdot2)
  return __builtin_amdgcn_fdot2(al.h, bl.h,
         __builtin_amdgcn_fdot2(ah.h, bh.h, 0.f, false), false);
#else
  return (float)al.h[0] * (float)bl.h[0] + (float)al.h[1] * (float)bl.h[1] +
         (float)ah.h[0] * (float)bh.h[0] + (float)ah.h[1] * (float)bh.h[1];
#endif
}

// ---------------------------------------------------------------------------
// Kernel P: pack W (f32) into per-lane MFMA B-fragments (fp16).
// Wk pre-scaled by sqrt(log2 e) so gathered score dots land in exp2 domain.
// idx < 1024: Wk table; idx >= 1024: Wv table. 2048 entries x 16 B = 32 KB.
// ---------------------------------------------------------------------------
__global__ void bfrag_kernel(const float* __restrict__ Wk,
                             const float* __restrict__ Wv,
                             _Float16* __restrict__ bfrag) {
  const int idx = blockIdx.x * 256 + threadIdx.x;
  if (idx >= 2048) return;
  const int which = idx >> 10;
  const float* __restrict__ W = which ? Wv : Wk;
  const float scale = which ? 1.0f : SQRT_LOG2E;
  const int li = idx & 1023;
  const int lane = li & 63;
  const int nt = (li >> 6) & 3;
  const int k0i = li >> 8;
  const int col = nt * 16 + (lane & 15);
  const int kbase = k0i * 32 + (lane >> 4) * 8;
  half8 h;
#pragma unroll
  for (int j = 0; j < 8; ++j)
    h[j] = (_Float16)(W[(size_t)(kbase + j) * D_OUT + col] * scale);
  reinterpret_cast<half8*>(bfrag)[idx] = h;
}

// ---------------------------------------------------------------------------
// Kernel A: H = X @ W + b via mfma_f32_16x16x32_f16.
// One wave = 16 rows x 64 cols (4 col-tiles x 4 K-steps = 16 MFMAs).
// C/D: col = lane&15 (+nt*16), row = r0 + (lane>>4)*4 + r   [m89 mapping]
// which==0 -> fp16 hk (pre-scaled by sqrt(log2e)); which==1 -> bf16 hv.
// ---------------------------------------------------------------------------
__global__ __launch_bounds__(256) void linear_mfma_kernel(
    const float* __restrict__ Xk, const float* __restrict__ Xv,
    const float* __restrict__ Wk, const float* __restrict__ bk,
    const float* __restrict__ Wv, const float* __restrict__ bv,
    const _Float16* __restrict__ bfrag, unsigned short* __restrict__ hkv,
    int R, int nblk) {
  const int which = (blockIdx.x >= nblk) ? 1 : 0;
  const int blk = blockIdx.x - which * nblk;
  const float* __restrict__ X = which ? Xv : Xk;
  const float* __restrict__ bias = which ? bv : bk;
  const float bscale = which ? 1.0f : SQRT_LOG2E;
  const int uoff = which ? D_OUT : 0;

  const int wave = threadIdx.x >> 6;
  const int lane = threadIdx.x & 63;
  const int r0 = (blk * 4 + wave) * 16;
  if (r0 >= R) return;
  const int rowi = lane & 15;
  const int kgrp = lane >> 4;

  if (r0 + 16 <= R) {
    const half8* btab =
        reinterpret_cast<const half8*>(bfrag) + (which ? 1024 : 0);
    half8 bf[4][4];
#pragma unroll
    for (int k0i = 0; k0i < 4; ++k0i)
#pragma unroll
      for (int nt = 0; nt < 4; ++nt)
        bf[k0i][nt] = btab[(k0i * 4 + nt) * 64 + lane];

    f32x4 acc[4];
#pragma unroll
    for (int nt = 0; nt < 4; ++nt) acc[nt] = (f32x4){0.f, 0.f, 0.f, 0.f};

    const float* xrow = X + (size_t)(r0 + rowi) * D_IN;
#pragma unroll
    for (int k0i = 0; k0i < 4; ++k0i) {
      const float4 x0 =
          *reinterpret_cast<const float4*>(xrow + k0i * 32 + kgrp * 8);
      const float4 x1 =
          *reinterpret_cast<const float4*>(xrow + k0i * 32 + kgrp * 8 + 4);
      half8 a;
      a[0] = (_Float16)x0.x; a[1] = (_Float16)x0.y;
      a[2] = (_Float16)x0.z; a[3] = (_Float16)x0.w;
      a[4] = (_Float16)x1.x; a[5] = (_Float16)x1.y;
      a[6] = (_Float16)x1.z; a[7] = (_Float16)x1.w;
#pragma unroll
      for (int nt = 0; nt < 4; ++nt)
        acc[nt] = __builtin_amdgcn_mfma_f32_16x16x32_f16(a, bf[k0i][nt],
                                                         acc[nt], 0, 0, 0);
    }
#pragma unroll
    for (int nt = 0; nt < 4; ++nt) {
      const int col = nt * 16 + rowi;
      const float bcol = bias[col] * bscale;
#pragma unroll
      for (int r = 0; r < 4; ++r) {
        const int row = r0 + kgrp * 4 + r;
        const float val = acc[nt][r] + bcol;
        hkv[(size_t)row * ROWH + uoff + col] =
            which ? f2bf(val) : f2h(val);
      }
    }
  } else {
    // tail rows (R%16 != 0 only): direct f32 dot, lane = column
    const float* __restrict__ W = which ? Wv : Wk;
    for (int r = r0; r < R; ++r) {
      const float* xr = X + (size_t)r * D_IN;
      float acc = bias[lane];
      for (int k = 0; k < D_IN; ++k)
        acc = fmaf(xr[k], W[(size_t)k * D_OUT + lane], acc);
      acc *= bscale;
      hkv[(size_t)r * ROWH + uoff + lane] = which ? f2bf(acc) : f2h(acc);
    }
  }
}

// ---------------------------------------------------------------------------
// Kernel B: CSR row pointers from sorted dst. row_ptr[i] = lower_bound(dst, i)
// ---------------------------------------------------------------------------
__global__ void rowptr_kernel(const int* __restrict__ dst, int E, int N,
                              int* __restrict__ row_ptr) {
  int i = blockIdx.x * blockDim.x + threadIdx.x;
  if (i > N) return;
  int lo = 0, hi = E;
  while (lo < hi) {
    int mid = (lo + hi) >> 1;
    if (dst[mid] < i) lo = mid + 1; else hi = mid;
  }
  row_ptr[i] = lo;
}

// ---------------------------------------------------------------------------
// sum over each 16-lane row via DPP rotate-adds (pure VALU).
// ---------------------------------------------------------------------------
__device__ __forceinline__ float rowsum16(float p) {
  union { float f; int i; } u, v;
  u.f = p;
  v.i = __builtin_amdgcn_update_dpp(0, u.i, 0x121, 0xF, 0xF, true);  // row_ror:1
  u.f += v.f;
  v.i = __builtin_amdgcn_update_dpp(0, u.i, 0x122, 0xF, 0xF, true);  // row_ror:2
  u.f += v.f;
  v.i = __builtin_amdgcn_update_dpp(0, u.i, 0x124, 0xF, 0xF, true);  // row_ror:4
  u.f += v.f;
  v.i = __builtin_amdgcn_update_dpp(0, u.i, 0x128, 0xF, 0xF, true);  // row_ror:8
  u.f += v.f;
  return u.f;
}

// online-softmax state, exp2 domain (hk pre-scaled so dot is log2-weighted)
struct SMState { float m, l; float4 a; };

// branchy update: common path = 1 exp2 + 5 fma; rescale only on new max
// (pl is uniform across the 16-lane group -> clean exec-mask branch)
__device__ __forceinline__ void sm_update(SMState& st, float pl,
                                          const uint2& vu) {
  if (pl > st.m) {
    const float sc = exp2f(st.m - pl);  // first edge: exp2(-inf) = 0
    st.l *= sc;
    st.a.x *= sc; st.a.y *= sc; st.a.z *= sc; st.a.w *= sc;
    st.m = pl;
  }
  const float a = exp2f(pl - st.m);
  const float4 vs = unpack_bf4(vu);
  st.l += a;
  st.a.x = fmaf(a, vs.x, st.a.x);
  st.a.y = fmaf(a, vs.y, st.a.y);
  st.a.z = fmaf(a, vs.z, st.a.z);
  st.a.w = fmaf(a, vs.w, st.a.w);
}

__device__ __forceinline__ void sm_merge(SMState& d, const SMState& s) {
  const float mn = fmaxf(d.m, s.m);
  const float s1 = exp2f(d.m - mn);
  const float s2 = exp2f(s.m - mn);
  d.l = d.l * s1 + s.l * s2;
  d.a.x = d.a.x * s1 + s.a.x * s2;
  d.a.y = d.a.y * s1 + s.a.y * s2;
  d.a.z = d.a.z * s1 + s.a.z * s2;
  d.a.w = d.a.w * s1 + s.a.w * s2;
  d.m = mn;
}

__device__ __forceinline__ void sm_merge_xor(SMState& d, int off) {
  SMState s;
  s.m = __shfl_xor(d.m, off, 64);
  s.l = __shfl_xor(d.l, off, 64);
  s.a.x = __shfl_xor(d.a.x, off, 64);
  s.a.y = __shfl_xor(d.a.y, off, 64);
  s.a.z = __shfl_xor(d.a.z, off, 64);
  s.a.w = __shfl_xor(d.a.w, off, 64);
  sm_merge(d, s);
}

// ---------------------------------------------------------------------------
// Kernel C: per-node segmented online-softmax aggregation, BOTH batches per
// wave. 4 groups of 16 lanes; per group 2 ILP states x 2 batches. Per
// iteration all 8 row-loads are issued BEFORE any (branchy) compute.
// hk fp16 (pre-scaled to exp2 domain) via v_dot2_f32_f16; hv bf16.
// [measured-optimal: 68.2 us, VALUBusy ~86%, 180 MB @ 3.08 TB/s — both
//  pipes at their demonstrated limits for this access pattern]
// ---------------------------------------------------------------------------
__global__ __launch_bounds__(256) void aggregate_kernel(
    const unsigned short* __restrict__ hkv, const int* __restrict__ src,
    const int* __restrict__ row_ptr, float* __restrict__ out, int N) {
  const int node = blockIdx.x * 4 + (threadIdx.x >> 6);
  const int lane = threadIdx.x & 63;
  if (node >= N) return;
  const unsigned short* hb0 = hkv;
  const unsigned short* hb1 = hkv + (size_t)N * ROWH;

  const int li = lane & 15;  // dim-quad index (uint2 granule)
  const int g = lane >> 4;   // edge group

  const uint2 kd0 = reinterpret_cast<const uint2*>(hb0 + (size_t)node * ROWH)[li];
  const uint2 kd1 = reinterpret_cast<const uint2*>(hb1 + (size_t)node * ROWH)[li];
  const int e0 = row_ptr[node];
  const int e1 = row_ptr[node + 1];

  SMState A0 = {-FLT_MAX, 0.f, {0.f, 0.f, 0.f, 0.f}};
  SMState B0 = A0, A1 = A0, B1 = A0;

  int e = e0 + g;
  for (; e + 4 < e1; e += 8) {
    const int sA = src[e];
    const int sB = src[e + 4];
    const uint2* rA0 = reinterpret_cast<const uint2*>(hb0 + (size_t)sA * ROWH);
    const uint2* rA1 = reinterpret_cast<const uint2*>(hb1 + (size_t)sA * ROWH);
    const uint2* rB0 = reinterpret_cast<const uint2*>(hb0 + (size_t)sB * ROWH);
    const uint2* rB1 = reinterpret_cast<const uint2*>(hb1 + (size_t)sB * ROWH);
    const uint2 kA0 = rA0[li], vA0 = rA0[16 + li];
    const uint2 kA1 = rA1[li], vA1 = rA1[16 + li];
    const uint2 kB0 = rB0[li], vB0 = rB0[16 + li];
    const uint2 kB1 = rB1[li], vB1 = rB1[16 + li];

    const float plA0 = rowsum16(hdot4(kA0, kd0));
    const float plA1 = rowsum16(hdot4(kA1, kd1));
    const float plB0 = rowsum16(hdot4(kB0, kd0));
    const float plB1 = rowsum16(hdot4(kB1, kd1));

    sm_update(A0, plA0, vA0);
    sm_update(A1, plA1, vA1);
    sm_update(B0, plB0, vB0);
    sm_update(B1, plB1, vB1);
  }
  if (e < e1) {
    const int sA = src[e];
    const uint2* rA0 = reinterpret_cast<const uint2*>(hb0 + (size_t)sA * ROWH);
    const uint2* rA1 = reinterpret_cast<const uint2*>(hb1 + (size_t)sA * ROWH);
    const uint2 kA0 = rA0[li], vA0 = rA0[16 + li];
    const uint2 kA1 = rA1[li], vA1 = rA1[16 + li];
    const float plA0 = rowsum16(hdot4(kA0, kd0));
    const float plA1 = rowsum16(hdot4(kA1, kd1));
    sm_update(A0, plA0, vA0);
    sm_update(A1, plA1, vA1);
  }

  sm_merge(A0, B0);
  sm_merge(A1, B1);
  sm_merge_xor(A0, 16); sm_merge_xor(A0, 32);
  sm_merge_xor(A1, 16); sm_merge_xor(A1, 32);

  if (lane < 16) {
#pragma unroll
    for (int b = 0; b < 2; ++b) {
      const SMState& S = b ? A1 : A0;
      const float denom = (S.l == 0.f) ? 1.f : S.l;
      float4 o;
      o.x = S.a.x / denom; o.y = S.a.y / denom;
      o.z = S.a.z / denom; o.w = S.a.w / denom;
      o.x = (o.x >= 0.f) ? o.x : NEG_SLOPE * o.x;
      o.y = (o.y >= 0.f) ? o.y : NEG_SLOPE * o.y;
      o.z = (o.z >= 0.f) ? o.z : NEG_SLOPE * o.z;
      o.w = (o.w >= 0.f) ? o.w : NEG_SLOPE * o.w;
      *reinterpret_cast<float4*>(out + ((size_t)b * N + node) * D_OUT + 4 * lane) = o;
    }
  }
}

// ---------------------------------------------------------------------------
extern "C" void kernel_launch(void* const* d_in, const int* in_sizes, int n_in,
                              void* d_out, int out_size, void* d_ws,
                              size_t ws_size, hipStream_t stream) {
  const float* X_key   = (const float*)d_in[0];
  const float* X_value = (const float*)d_in[1];
  const float* Wk      = (const float*)d_in[2];
  const float* bk      = (const float*)d_in[3];
  const float* Wv      = (const float*)d_in[4];
  const float* bv      = (const float*)d_in[5];
  const int*   src     = (const int*)d_in[6];
  const int*   dst     = (const int*)d_in[7];
  float* out = (float*)d_out;

  const int B = 2;
  const int R = in_sizes[0] / D_IN;  // B*N rows
  const int N = R / B;
  const int E = in_sizes[6];

  // workspace: bfrag 32KB (16B-aligned) | hkv ushort[R][128] | row_ptr
  _Float16* bfrag = (_Float16*)d_ws;
  unsigned short* hkv = (unsigned short*)((char*)d_ws + 32768);
  int* row_ptr = (int*)(hkv + (size_t)R * ROWH);

  const int blocksB = (N + 1 + 255) / 256;
  hipLaunchKernelGGL(rowptr_kernel, dim3(blocksB), dim3(256), 0, stream,
                     dst, E, N, row_ptr);
  hipLaunchKernelGGL(bfrag_kernel, dim3(8), dim3(256), 0, stream,
                     Wk, Wv, bfrag);
  const int wavesPerMat = (R + 15) / 16;
  const int nblk = (wavesPerMat + 3) / 4;
  hipLaunchKernelGGL(linear_mfma_kernel, dim3(2 * nblk), dim3(256), 0, stream,
                     X_key, X_value, Wk, bk, Wv, bv, bfrag, hkv, R, nblk);
  const int blocksC = (N + 3) / 4;  // one wave per node, both batches
  hipLaunchKernelGGL(aggregate_kernel, dim3(blocksC), dim3(256), 0, stream,
                     hkv, src, row_ptr, out, N);
}